// Round 4
// baseline (447.313 us; speedup 1.0000x reference)
//
#include <hip/hip_runtime.h>

// Problem constants (fixed by the reference)
#define MM 8192
#define NN 4096
#define KK 4096

// GEMM tiling: block 128x128, 4 waves in 2x2, wave tile 64x64 as a 2x2 grid
// of v_mfma_i32_32x32x32_i8. NO LDS, NO barriers in the K-loop: both
// operands are pre-shuffled (by pack_kernel) into MFMA-fragment order so
// every fragment load is one fully-coalesced global_load_dwordx4 (1 KB/wave)
// served from L2/L3, and loads stay in flight across the whole K-loop
// (software-pipelined, prefetch distance 2).
#define BM 128
#define BN 128

typedef int int32x4  __attribute__((ext_vector_type(4)));
typedef int int32x16 __attribute__((ext_vector_type(16)));

// ---------------------------------------------------------------------------
// Pack kernel: int32 (int8-range) -> int8, subtract zero point, AND shuffle
// into MFMA fragment order:
//   tensor[row][k]  ->  chunk( rt = row>>5, ks = k>>5 ) of 1024 B,
//   byte offset l*16 + (k&15), where l = (row&31) + 32*((k>>4)&1).
// This is exactly the A/B operand layout of mfma_i32_32x32x32_i8
// (lane l holds row l&31, k-bytes (l>>5)*16 + j  — same pattern verified for
// 16x16x64_i8 in R1/R2). Chunks ordered [row_tile][k_step].
// 4 elements/thread: one int4 load (wave reads 1 KB contiguous), one 4B
// store. A/W boundary is block-aligned. k0=4t covers j = (r4&3)*4..+3, which
// never crosses a 16B fragment boundary -> single int store.
// ---------------------------------------------------------------------------
__global__ __launch_bounds__(256) void pack_kernel(
    const int* __restrict__ a, const int* __restrict__ w,
    char* __restrict__ a8s, char* __restrict__ b8s,
    const int* __restrict__ izp, const int* __restrict__ wzp) {
  const long tid = (long)blockIdx.x * 256 + threadIdx.x;
  const long A_T = (long)MM * KK / 4;

  const int4* src;
  int* dstbase;
  long row;
  int r4, z;
  if (tid < A_T) {
    src = (const int4*)a + tid;
    dstbase = (int*)a8s;
    row = tid >> 10;           // K/4 = 1024 threads per row
    r4  = (int)(tid & 1023);
    z = izp[0];
  } else {
    const long t = tid - A_T;
    src = (const int4*)w + t;
    dstbase = (int*)b8s;
    row = t >> 10;
    r4  = (int)(t & 1023);
    z = wzp[row];
  }
  // k0 = r4*4;  ks = k0>>5 = r4>>3;  half = (k0>>4)&1 = (r4>>2)&1;
  // l = (row&31) + 32*half;  j/4 = r4&3
  const int  ks = r4 >> 3;
  const int  l  = ((int)row & 31) + (((r4 >> 2) & 1) << 5);
  const long didx = ((((row >> 5) << 7) + ks) << 8) + l * 4 + (r4 & 3);

  int4 v = *src;
  union { char c[4]; int q; } u;
  u.c[0] = (char)(v.x - z);
  u.c[1] = (char)(v.y - z);
  u.c[2] = (char)(v.z - z);
  u.c[3] = (char)(v.w - z);
  dstbase[didx] = u.q;
}

// ---------------------------------------------------------------------------
// Barrier-free int8 GEMM on pre-shuffled operands.
//   C[m][n] = sum_k A[m][k]*W[n][k];  out = is * ws[n] * C + bias[n]
// ---------------------------------------------------------------------------
__global__ __launch_bounds__(256, 3) void qgemm_kernel(
    const char* __restrict__ A8S, const char* __restrict__ B8S,
    float* __restrict__ out,
    const float* __restrict__ bias,
    const float* __restrict__ is_ptr,
    const float* __restrict__ wscale) {
  // ---- block swizzle: XCD-contiguous + grouped (GM=8), as R2 (verified) --
  int pid = blockIdx.x;
  pid = (pid & 7) * 256 + (pid >> 3);      // XCD x owns pids [256x, 256x+256)
  const int bm = (pid >> 8) * 8 + (pid & 7);  // 0..63
  const int bn = (pid & 255) >> 3;            // 0..31

  const int tid  = threadIdx.x;
  const int wave = tid >> 6;
  const int lane = tid & 63;
  const int wm = (wave >> 1) * 64;  // wave tile origin: 2x2 grid of 64x64
  const int wn = (wave & 1) * 64;

  // fragment-chunk base pointers: chunk stride along k is 1024 B, a row-tile
  // owns 128 chunks (KK/32) = 1<<17 B.
  const int mt0 = bm * 4 + (wm >> 5);  // global 32-row tile index, mi=0
  const int nt0 = bn * 4 + (wn >> 5);
  const int lo  = lane * 16;
  const char* aB0 = A8S + ((long)(mt0    ) << 17) + lo;
  const char* aB1 = A8S + ((long)(mt0 + 1) << 17) + lo;
  const char* bB0 = B8S + ((long)(nt0    ) << 17) + lo;
  const char* bB1 = B8S + ((long)(nt0 + 1) << 17) + lo;

// fragment load for k-step starting at k (multiple of 32): chunk (k>>5)*1024
#define LD(base, k) (*(const int32x4*)((base) + ((long)(k) << 5)))
#define MFMA(a, b, c) __builtin_amdgcn_mfma_i32_32x32x32_i8((a), (b), (c), 0, 0, 0)

  int32x16 acc00 = (int32x16)0, acc01 = (int32x16)0;
  int32x16 acc10 = (int32x16)0, acc11 = (int32x16)0;

  // 4 in-flight fragment sets, prefetch distance 2 (k-steps of 32).
  int32x4 a0[2], b0[2], a1[2], b1[2], a2[2], b2[2], a3[2], b3[2];
  a0[0] = LD(aB0, 0);  a0[1] = LD(aB1, 0);
  b0[0] = LD(bB0, 0);  b0[1] = LD(bB1, 0);
  a1[0] = LD(aB0, 32); a1[1] = LD(aB1, 32);
  b1[0] = LD(bB0, 32); b1[1] = LD(bB1, 32);

  for (int kk = 0; kk < KK; kk += 128) {
    const int k2 = kk + 64;
    a2[0] = LD(aB0, k2); a2[1] = LD(aB1, k2);
    b2[0] = LD(bB0, k2); b2[1] = LD(bB1, k2);
    acc00 = MFMA(a0[0], b0[0], acc00);
    acc01 = MFMA(a0[0], b0[1], acc01);
    acc10 = MFMA(a0[1], b0[0], acc10);
    acc11 = MFMA(a0[1], b0[1], acc11);

    const int k3 = kk + 96;
    a3[0] = LD(aB0, k3); a3[1] = LD(aB1, k3);
    b3[0] = LD(bB0, k3); b3[1] = LD(bB1, k3);
    acc00 = MFMA(a1[0], b1[0], acc00);
    acc01 = MFMA(a1[0], b1[1], acc01);
    acc10 = MFMA(a1[1], b1[0], acc10);
    acc11 = MFMA(a1[1], b1[1], acc11);

    const int k4 = (kk + 128 < KK) ? kk + 128 : 0;  // uniform clamp (dead loads on last iter)
    a0[0] = LD(aB0, k4); a0[1] = LD(aB1, k4);
    b0[0] = LD(bB0, k4); b0[1] = LD(bB1, k4);
    acc00 = MFMA(a2[0], b2[0], acc00);
    acc01 = MFMA(a2[0], b2[1], acc01);
    acc10 = MFMA(a2[1], b2[0], acc10);
    acc11 = MFMA(a2[1], b2[1], acc11);

    const int k5 = (kk + 160 < KK) ? kk + 160 : 0;
    a1[0] = LD(aB0, k5); a1[1] = LD(aB1, k5);
    b1[0] = LD(bB0, k5); b1[1] = LD(bB1, k5);
    acc00 = MFMA(a3[0], b3[0], acc00);
    acc01 = MFMA(a3[0], b3[1], acc01);
    acc10 = MFMA(a3[1], b3[0], acc10);
    acc11 = MFMA(a3[1], b3[1], acc11);
  }

  // ---- epilogue: out = is * ws[n] * acc + bias[n] -----------------------
  // C/D layout (32x32): col = lane&31, row = (reg&3) + 8*(reg>>2) + 4*(lane>>5)
  const float is0 = is_ptr[0];
  const int colb = bn * BN + wn + (lane & 31);
  const int rowb = bm * BM + wm + 4 * (lane >> 5);
#pragma unroll
  for (int ni = 0; ni < 2; ++ni) {
    const int col = colb + ni * 32;
    const float s = is0 * wscale[col];
    const float bv = bias[col];
#pragma unroll
    for (int mi = 0; mi < 2; ++mi) {
      const int32x16 A = (mi == 0) ? (ni == 0 ? acc00 : acc01)
                                   : (ni == 0 ? acc10 : acc11);
      const int row0 = rowb + mi * 32;
#pragma unroll
      for (int r = 0; r < 16; ++r) {
        const int row = row0 + (r & 3) + 8 * (r >> 2);
        out[(long)row * NN + col] = (float)A[r] * s + bv;
      }
    }
  }
}

// ---------------------------------------------------------------------------
extern "C" void kernel_launch(void* const* d_in, const int* in_sizes, int n_in,
                              void* d_out, int out_size, void* d_ws, size_t ws_size,
                              hipStream_t stream) {
  const int*   inp    = (const int*)d_in[0];    // [M,K] int32 (int8-range)
  const int*   weight = (const int*)d_in[1];    // [N,K] int32 (int8-range)
  const float* bias   = (const float*)d_in[2];  // [N]
  const float* iscale = (const float*)d_in[3];  // [1]
  const int*   izp    = (const int*)d_in[4];    // [1]
  const float* wscale = (const float*)d_in[5];  // [N]
  const int*   wzp    = (const int*)d_in[6];    // [N]
  float* out = (float*)d_out;

  char* a8s = (char*)d_ws;                       // M*K  = 33.55 MB (shuffled)
  char* b8s = a8s + (size_t)MM * KK;             // N*K  = 16.78 MB (shuffled)

  // pack+shuffle: (M*K + N*K)/4 threads -> 49152 blocks of 256 (exact)
  pack_kernel<<<49152, 256, 0, stream>>>(inp, weight, a8s, b8s, izp, wzp);

  // GEMM: 64 m-tiles * 32 n-tiles = 2048 blocks of 256
  qgemm_kernel<<<2048, 256, 0, stream>>>(a8s, b8s, out, bias, iscale, wscale);
}